// Round 11
// baseline (389.948 us; speedup 1.0000x reference)
//
#include <hip/hip_runtime.h>

typedef _Float16 half8 __attribute__((ext_vector_type(8)));
typedef _Float16 half4 __attribute__((ext_vector_type(4)));
typedef float f32x4 __attribute__((ext_vector_type(4)));

#define TT 512
#define HH 64
#define MB 8      // real batches per block -> 256 blocks; cols 8..15 select tile p=1
#define S  120    // state row stride (halfs): 60 dwords == 28 mod 32 -> 8 distinct row banks
#define XS 4112   // xbuf per-batch stride (halfs): 514*8 -> pad absorbs t+2 prefetch

// gapped h layout: pos(k) = k + 2*(k>>2)  (2-half gap every 4 halfs)
// -> b64 reads are 8B-aligned with start banks spread over even+odd mod-4 residues:
//    every LDS phase <=2-way (free), vs b128's inherent 4-way (16B align => start==0 mod 4)
#define HPOS(k) ((k) + 2 * ((k) >> 2))

__global__ __launch_bounds__(512, 1)
void lstm_v22(const float* __restrict__ x,
              const float* __restrict__ W_ih,
              const float* __restrict__ W_hh,
              const float* __restrict__ b_ih,
              const float* __restrict__ b_hh,
              const float* __restrict__ W_fc,
              const float* __restrict__ b_fc,
              float* __restrict__ out)
{
    __shared__ __align__(16) _Float16 st[2][8 * S];      // 3840 B: h state (gapped), dbuf
    __shared__ __align__(16) _Float16 xbuf[MB * XS];     // 65792 B: pre-packed x B-frags

    const int tid = threadIdx.x;
    const int w   = tid >> 6;      // wave 0..7
    const int l   = tid & 63;
    const int q   = l >> 4;
    const int col = l & 15;
    const int b0  = blockIdx.x * MB;
    const int xcol = col & 7;      // cols 8..15 share a real batch's B-column
    const bool lo = (col < 8);

    const float kN = -1.4426950408889634f;   // -log2(e)
    const float kP =  2.8853900817779268f;   // +2*log2(e)

    // ---- persistent A fragments (weights), 2 tiles per wave ----
    // tile p of wave w covers gate-rows r(m) = 64*(m&3) + 8w + 2*(m>>2) + p
    // => lane (q,col) reg j = gate j of unit u = 8w + 2q + p  (batch col&7)
    //    C is column-identical across col-halves (B cols 8..15 broadcast), so
    //    lane col>=8 holds tile p=1's gates for batch col-8 locally: select is
    //    4 cndmask, no cross-lane (v19/v20-verified).
    // Weights PRESCALED by exp2 constants (f32 mul BEFORE f16 cvt: single rounding).
    half8 aw[2][3];
    #pragma unroll
    for (int p = 0; p < 2; ++p) {
        const int r = 64 * (col & 3) + 8 * w + 2 * (col >> 2) + p;
        const float scale = ((col & 3) == 2) ? kP : kN;   // gate g -> kP, i/f/o -> kN
        #pragma unroll
        for (int c = 0; c < 2; ++c) {
            const float* src = W_hh + r * HH + 32 * c + 8 * q;
            half8 v;
            #pragma unroll
            for (int j = 0; j < 8; ++j) v[j] = (_Float16)(src[j] * scale);
            aw[p][c] = v;
        }
        half8 v = {};
        if (q == 0) {   // k=64..67 -> W_ih, k=68 -> bias (B supplies 1.0 at k=68)
            #pragma unroll
            for (int j = 0; j < 4; ++j) v[j] = (_Float16)(W_ih[r * 4 + j] * scale);
            v[4] = (_Float16)((b_ih[r] + b_hh[r]) * scale);
        }
        aw[p][2] = v;
    }

    // ---- pre-stage x as ready-to-use B-frags: {x0,x1,x2,x3,1,0,0,0} per (b,t) ----
    #pragma unroll
    for (int it = 0; it < (MB * TT) / 512; ++it) {
        const int task = tid + it * 512;
        const int b = task >> 9, t = task & 511;
        float4 v = *(const float4*)(x + ((size_t)(b0 + b) * TT + t) * 4);
        half8 hx;
        hx[0] = (_Float16)v.x; hx[1] = (_Float16)v.y;
        hx[2] = (_Float16)v.z; hx[3] = (_Float16)v.w;
        hx[4] = (_Float16)1.0f; hx[5] = (_Float16)0.f;
        hx[6] = (_Float16)0.f;  hx[7] = (_Float16)0.f;
        *(half8*)&xbuf[b * XS + t * 8] = hx;
    }

    // ---- zero h state (both buffers, all 8 rows incl. gaps) ----
    for (int i = tid; i < 2 * 8 * S; i += 512) (&st[0][0])[i] = (_Float16)0.f;
    __syncthreads();

    float cs2 = 0.f;               // carried state = kP * c  (folds the EC multiply)
    // write addr: unit u = 8w + 2q + (col>>3) stored at gapped position
    const int wrow = xcol * S + HPOS(8 * w + 2 * q + (col >> 3));
    const f32x4 z4 = {0.f, 0.f, 0.f, 0.f};

    // x-pipeline: accx* = x-contribution for step t (ready); bxn = B-frag for step t+1
    f32x4 accx0, accx1;
    half8 bxn;
    {
        half8 bx0 = *(const half8*)&xbuf[xcol * XS + 0];
        accx0 = __builtin_amdgcn_mfma_f32_16x16x32_f16(aw[0][2], bx0, z4, 0, 0, 0);
        accx1 = __builtin_amdgcn_mfma_f32_16x16x32_f16(aw[1][2], bx0, z4, 0, 0, 0);
        bxn = *(const half8*)&xbuf[xcol * XS + 8];
    }

    #pragma unroll 4
    for (int t = 0; t < TT; ++t) {
        const int rb = t & 1, wb = rb ^ 1;
        const _Float16* sr = &st[rb][xcol * S];

        // ---- critical reads first: 4x ds_read_b64 (gapped, <=2-way banks: free) ----
        // h[8q..8q+3] at HPOS(8q)=12q; h[8q+4..8q+7] at 12q+6  (gap prevents b128 merge)
        half4 lo0 = *(const half4*)(sr + 12 * q);
        half4 hi0 = *(const half4*)(sr + 12 * q + 6);
        // h[32+8q..] at HPOS(32+8q)=48+12q; +4 at 48+12q+6
        half4 lo1 = *(const half4*)(sr + 48 + 12 * q);
        half4 hi1 = *(const half4*)(sr + 48 + 12 * q + 6);

        // ---- x-MFMAs for t+1: operands in regs -> issue inside read latency ----
        f32x4 axn0 = __builtin_amdgcn_mfma_f32_16x16x32_f16(aw[0][2], bxn, z4, 0, 0, 0);
        f32x4 axn1 = __builtin_amdgcn_mfma_f32_16x16x32_f16(aw[1][2], bxn, z4, 0, 0, 0);

        bxn = *(const half8*)&xbuf[xcol * XS + (t + 2) * 8];     // prefetch (pad-safe)

        // reassemble MFMA B-operands (register concat)
        half8 bh0 = __builtin_shufflevector(lo0, hi0, 0, 1, 2, 3, 4, 5, 6, 7);
        half8 bh1 = __builtin_shufflevector(lo1, hi1, 0, 1, 2, 3, 4, 5, 6, 7);

        // ---- h-MFMAs: chained (issue-minimal; latency hidden by partner wave) ----
        f32x4 a0 = __builtin_amdgcn_mfma_f32_16x16x32_f16(aw[0][0], bh0, accx0, 0, 0, 0);
        f32x4 a1 = __builtin_amdgcn_mfma_f32_16x16x32_f16(aw[1][0], bh0, accx1, 0, 0, 0);
        a0 = __builtin_amdgcn_mfma_f32_16x16x32_f16(aw[0][1], bh1, a0, 0, 0, 0);
        a1 = __builtin_amdgcn_mfma_f32_16x16x32_f16(aw[1][1], bh1, a1, 0, 0, 0);

        // ---- select own tile (4 cndmask; cols>=8 hold batch col-8 locally) ----
        const float gi = lo ? a0[0] : a1[0];   // prescaled by kN
        const float gf = lo ? a0[1] : a1[1];   // prescaled by kN
        const float gg = lo ? a0[2] : a1[2];   // prescaled by kP
        const float go = lo ? a0[3] : a1[3];   // prescaled by kN

        const float EI = __builtin_amdgcn_exp2f(gi);
        const float EF = __builtin_amdgcn_exp2f(gf);
        const float EG = __builtin_amdgcn_exp2f(gg);
        const float rF = __builtin_amdgcn_rcpf(1.f + EF);
        const float r1 = __builtin_amdgcn_rcpf((1.f + EI) * (EG + 1.f));
        const float Yn = __builtin_fmaf(kP, EG, -kP);  // kP*(EG-1) as one fma
        const float Y  = Yn * r1;
        cs2 = cs2 * rF + Y;                            // cs2 == kP * c
        const float EO = __builtin_amdgcn_exp2f(go);
        const float EC = __builtin_amdgcn_exp2f(cs2);
        const float r2 = __builtin_amdgcn_rcpf((1.f + EO) * (EC + 1.f));
        const float hn = (EC - 1.f) * r2;

        st[wb][wrow] = (_Float16)hn;
        __syncthreads();

        accx0 = axn0; accx1 = axn1;
    }

    // ---- FC epilogue: final h in st[0] (TT even, gapped layout) ----
    if (tid < MB * 4) {
        const int b = tid >> 2, o = tid & 3;
        float s = b_fc[o];
        const float* wf = W_fc + o * HH;
        #pragma unroll
        for (int k = 0; k < HH; ++k)
            s = fmaf((float)st[0][b * S + HPOS(k)], wf[k], s);
        out[(size_t)(b0 + b) * 4 + o] = s;
    }
}

extern "C" void kernel_launch(void* const* d_in, const int* in_sizes, int n_in,
                              void* d_out, int out_size, void* d_ws, size_t ws_size,
                              hipStream_t stream) {
    const float* x    = (const float*)d_in[0];
    const float* W_ih = (const float*)d_in[1];
    const float* W_hh = (const float*)d_in[2];
    const float* b_ih = (const float*)d_in[3];
    const float* b_hh = (const float*)d_in[4];
    const float* W_fc = (const float*)d_in[5];
    const float* b_fc = (const float*)d_in[6];
    float* out = (float*)d_out;
    lstm_v22<<<2048 / MB, 512, 0, stream>>>(x, W_ih, W_hh, b_ih, b_hh, W_fc, b_fc, out);
}

// Round 12
// 207.438 us; speedup vs baseline: 1.8798x; 1.8798x over previous
//
#include <hip/hip_runtime.h>

typedef _Float16 half8 __attribute__((ext_vector_type(8)));
typedef _Float16 half4 __attribute__((ext_vector_type(4)));
typedef float f32x4 __attribute__((ext_vector_type(4)));

#define TT 512
#define HH 64
#define MB 8      // real batches per block -> 256 blocks; cols 8..15 select tile p=1
#define S  88     // state row stride (halfs): h-writes bank-bijective
#define XS 4112   // xbuf per-batch stride (halfs): 514*8 -> pad absorbs t+2 prefetch

#define MFMA16(A, B, C) __builtin_amdgcn_mfma_f32_16x16x32_f16((A), (B), (C), 0, 0, 0)

__global__ __launch_bounds__(512, 1)
void lstm_v23(const float* __restrict__ x,
              const float* __restrict__ W_ih,
              const float* __restrict__ W_hh,
              const float* __restrict__ b_ih,
              const float* __restrict__ b_hh,
              const float* __restrict__ W_fc,
              const float* __restrict__ b_fc,
              float* __restrict__ out)
{
    __shared__ __align__(16) _Float16 st[2][8 * S];      // 2816 B: h state, dbuf
    __shared__ __align__(16) _Float16 xbuf[MB * XS];     // 65792 B: pre-packed x B-frags

    const int tid = threadIdx.x;
    const int w   = tid >> 6;      // wave 0..7
    const int l   = tid & 63;
    const int q   = l >> 4;
    const int col = l & 15;
    const int b0  = blockIdx.x * MB;
    const int xcol = col & 7;      // cols 8..15 share a real batch's B-column
    const bool lo = (col < 8);
    const bool oddw = (w & 1);     // per-wave-uniform: phase-skew selector

    const float kN = -1.4426950408889634f;   // -log2(e)
    const float kP =  2.8853900817779268f;   // +2*log2(e)

    // ---- persistent A fragments (weights), 2 tiles per wave ----
    // tile p of wave w covers gate-rows r(m) = 64*(m&3) + 8w + 2*(m>>2) + p
    // => lane (q,col) reg j = gate j of unit u = 8w + 2q + p  (batch col&7)
    //    C is column-identical across col-halves (B cols 8..15 broadcast), so
    //    lane col>=8 holds tile p=1's gates for batch col-8 locally: select is
    //    4 cndmask, no cross-lane (v19/v20-verified).
    // Weights PRESCALED by exp2 constants (f32 mul BEFORE f16 cvt: single rounding).
    half8 aw[2][3];
    #pragma unroll
    for (int p = 0; p < 2; ++p) {
        const int r = 64 * (col & 3) + 8 * w + 2 * (col >> 2) + p;
        const float scale = ((col & 3) == 2) ? kP : kN;   // gate g -> kP, i/f/o -> kN
        #pragma unroll
        for (int c = 0; c < 2; ++c) {
            const float* src = W_hh + r * HH + 32 * c + 8 * q;
            half8 v;
            #pragma unroll
            for (int j = 0; j < 8; ++j) v[j] = (_Float16)(src[j] * scale);
            aw[p][c] = v;
        }
        half8 v = {};
        if (q == 0) {   // k=64..67 -> W_ih, k=68 -> bias (B supplies 1.0 at k=68)
            #pragma unroll
            for (int j = 0; j < 4; ++j) v[j] = (_Float16)(W_ih[r * 4 + j] * scale);
            v[4] = (_Float16)((b_ih[r] + b_hh[r]) * scale);
        }
        aw[p][2] = v;
    }

    // ---- pre-stage x as ready-to-use B-frags: {x0,x1,x2,x3,1,0,0,0} per (b,t) ----
    #pragma unroll
    for (int it = 0; it < (MB * TT) / 512; ++it) {
        const int task = tid + it * 512;
        const int b = task >> 9, t = task & 511;
        float4 v = *(const float4*)(x + ((size_t)(b0 + b) * TT + t) * 4);
        half8 hx;
        hx[0] = (_Float16)v.x; hx[1] = (_Float16)v.y;
        hx[2] = (_Float16)v.z; hx[3] = (_Float16)v.w;
        hx[4] = (_Float16)1.0f; hx[5] = (_Float16)0.f;
        hx[6] = (_Float16)0.f;  hx[7] = (_Float16)0.f;
        *(half8*)&xbuf[b * XS + t * 8] = hx;
    }

    // ---- zero h state (both buffers, all 8 rows) ----
    for (int i = tid; i < 2 * 8 * S; i += 512) (&st[0][0])[i] = (_Float16)0.f;
    __syncthreads();

    float cs2 = 0.f;               // carried state = kP * c  (folds the EC multiply)
    const int wrow = xcol * S + 8 * w + 2 * q + (col >> 3);   // loop-invariant write addr
    const f32x4 z4 = {0.f, 0.f, 0.f, 0.f};

    // x-pipeline: accx* = x-contribution for step t (ready); bxn = B-frag for step t+1
    f32x4 accx0, accx1;
    half8 bxn;
    {
        half8 bx0 = *(const half8*)&xbuf[xcol * XS + 0];
        accx0 = MFMA16(aw[0][2], bx0, z4);
        accx1 = MFMA16(aw[1][2], bx0, z4);
        bxn = *(const half8*)&xbuf[xcol * XS + 8];
    }

    #pragma unroll 4
    for (int t = 0; t < TT; ++t) {
        const int rb = t & 1, wb = rb ^ 1;
        const _Float16* sr = &st[rb][0];

        half8 bh0, bh1;
        f32x4 axn0, axn1;

        // ---- per-wave phase skew: even waves read h first; odd waves issue the
        //      x-MFMA/prefetch block first, delaying their read->MFMA->trans
        //      pipeline so the two waves' quarter-rate bursts de-collide.
        //      Identical ops, identical math -> bit-identical results.
        if (!oddw) {
            bh0 = *(const half8*)&sr[xcol * S +      8 * q];   // k 0..31
            bh1 = *(const half8*)&sr[xcol * S + 32 + 8 * q];   // k 32..63
            axn0 = MFMA16(aw[0][2], bxn, z4);
            axn1 = MFMA16(aw[1][2], bxn, z4);
            bxn = *(const half8*)&xbuf[xcol * XS + (t + 2) * 8];
        } else {
            axn0 = MFMA16(aw[0][2], bxn, z4);
            axn1 = MFMA16(aw[1][2], bxn, z4);
            bxn = *(const half8*)&xbuf[xcol * XS + (t + 2) * 8];
            bh0 = *(const half8*)&sr[xcol * S +      8 * q];   // k 0..31
            bh1 = *(const half8*)&sr[xcol * S + 32 + 8 * q];   // k 32..63
        }

        // ---- h-MFMAs: chained (issue-minimal; latency hidden by partner wave) ----
        f32x4 a0 = MFMA16(aw[0][0], bh0, accx0);
        f32x4 a1 = MFMA16(aw[1][0], bh0, accx1);
        a0 = MFMA16(aw[0][1], bh1, a0);
        a1 = MFMA16(aw[1][1], bh1, a1);

        // ---- select own tile (4 cndmask; cols>=8 hold batch col-8 locally) ----
        const float gi = lo ? a0[0] : a1[0];   // prescaled by kN
        const float gf = lo ? a0[1] : a1[1];   // prescaled by kN
        const float gg = lo ? a0[2] : a1[2];   // prescaled by kP
        const float go = lo ? a0[3] : a1[3];   // prescaled by kN

        const float EI = __builtin_amdgcn_exp2f(gi);
        const float EF = __builtin_amdgcn_exp2f(gf);
        const float EG = __builtin_amdgcn_exp2f(gg);
        const float rF = __builtin_amdgcn_rcpf(1.f + EF);
        const float r1 = __builtin_amdgcn_rcpf((1.f + EI) * (EG + 1.f));
        const float Yn = __builtin_fmaf(kP, EG, -kP);  // kP*(EG-1) as one fma
        const float Y  = Yn * r1;
        cs2 = cs2 * rF + Y;                            // cs2 == kP * c
        const float EO = __builtin_amdgcn_exp2f(go);
        const float EC = __builtin_amdgcn_exp2f(cs2);
        const float r2 = __builtin_amdgcn_rcpf((1.f + EO) * (EC + 1.f));
        const float hn = (EC - 1.f) * r2;

        st[wb][wrow] = (_Float16)hn;    // bank-bijective across the wave
        __syncthreads();

        accx0 = axn0; accx1 = axn1;
    }

    // ---- FC epilogue: final h in st[0] (TT even) ----
    if (tid < MB * 4) {
        const int b = tid >> 2, o = tid & 3;
        float s = b_fc[o];
        const float* wf = W_fc + o * HH;
        #pragma unroll
        for (int k = 0; k < HH; ++k)
            s = fmaf((float)st[0][b * S + k], wf[k], s);
        out[(size_t)(b0 + b) * 4 + o] = s;
    }
}

extern "C" void kernel_launch(void* const* d_in, const int* in_sizes, int n_in,
                              void* d_out, int out_size, void* d_ws, size_t ws_size,
                              hipStream_t stream) {
    const float* x    = (const float*)d_in[0];
    const float* W_ih = (const float*)d_in[1];
    const float* W_hh = (const float*)d_in[2];
    const float* b_ih = (const float*)d_in[3];
    const float* b_hh = (const float*)d_in[4];
    const float* W_fc = (const float*)d_in[5];
    const float* b_fc = (const float*)d_in[6];
    float* out = (float*)d_out;
    lstm_v23<<<2048 / MB, 512, 0, stream>>>(x, W_ih, W_hh, b_ih, b_hh, W_fc, b_fc, out);
}